// Round 3
// baseline (928.638 us; speedup 1.0000x reference)
//
#include <hip/hip_runtime.h>

#define NVOX 500000
#define CIN 32
#define COUT 64
#define KK 27
#define EPSV 1e-5f

typedef __bf16 bf16x8 __attribute__((ext_vector_type(8)));
typedef float f32x4 __attribute__((ext_vector_type(4)));

__device__ __forceinline__ float bf2f(ushort u) {
    return __uint_as_float(((unsigned)u) << 16);
}
__device__ __forceinline__ ushort f2bf(float f) {
    unsigned u = __float_as_uint(f);
    unsigned r = (u + 0x7FFFu + ((u >> 16) & 1u)) >> 16;  // RNE
    return (ushort)r;
}
union U4BF { uint4 u; bf16x8 b; ushort s[8]; };
__device__ __forceinline__ bf16x8 as_bf8(uint4 v) { U4BF c; c.u = v; return c.b; }
__device__ __forceinline__ bf16x8 f8_to_bf8(float4 a, float4 b) {
    U4BF c;
    c.s[0] = f2bf(a.x); c.s[1] = f2bf(a.y); c.s[2] = f2bf(a.z); c.s[3] = f2bf(a.w);
    c.s[4] = f2bf(b.x); c.s[5] = f2bf(b.y); c.s[6] = f2bf(b.z); c.s[7] = f2bf(b.w);
    return c.b;
}

__device__ __forceinline__ float ldv(const float* p, long long i) { return p[i]; }
__device__ __forceinline__ float ldv(const ushort* p, long long i) { return bf2f(p[i]); }

// ---------------- prep: zero stats + sentinel rows, swizzle weights (f32 -> bf16 frags) ----
// W1s layout: [k][nt][lane][8]  (B-frag 16x16x32: lane holds B[k=(lane>>4)*8+j][n=nt*16+(lane&15)])
// W2s layout: [k][half][nt][lane][8]
// Wres_s:     [nt][lane][8]
__global__ void prep_kernel(const float* __restrict__ W1, const float* __restrict__ W2,
                            const float* __restrict__ Wres,
                            ushort* __restrict__ w1s, ushort* __restrict__ w2s,
                            ushort* __restrict__ wrs,
                            float* __restrict__ stats,
                            ushort* __restrict__ y1, ushort* __restrict__ y2) {
    int t = blockIdx.x * 256 + threadIdx.x;
    if (t < 192) { stats[t] = 0.f; return; }
    if (t < 224) { y1[(size_t)NVOX * CIN + (t - 192)] = 0; return; }
    if (t < 288) { y2[(size_t)NVOX * COUT + (t - 224)] = 0; return; }
    int d = t - 288;
    if (d < 27 * 4 * 64 * 8) {  // 55296
        int j = d & 7, lane = (d >> 3) & 63, nt = (d >> 9) & 3, k = d >> 11;
        int ci = ((lane >> 4) << 3) + j, co = (nt << 4) + (lane & 15);
        w1s[d] = f2bf(W1[(k * CIN + ci) * COUT + co]);
        return;
    }
    d -= 27 * 4 * 64 * 8;
    if (d < 27 * 2 * 4 * 64 * 8) {  // 110592
        int j = d & 7, lane = (d >> 3) & 63, nt = (d >> 9) & 3, half = (d >> 11) & 1, k = d >> 12;
        int ci = (half << 5) + ((lane >> 4) << 3) + j, co = (nt << 4) + (lane & 15);
        w2s[d] = f2bf(W2[(k * COUT + ci) * COUT + co]);
        return;
    }
    d -= 27 * 2 * 4 * 64 * 8;
    if (d < 4 * 64 * 8) {  // 2048
        int j = d & 7, lane = (d >> 3) & 63, nt = (d >> 9) & 3;
        int ci = ((lane >> 4) << 3) + j, co = (nt << 4) + (lane & 15);
        wrs[d] = f2bf(Wres[ci * COUT + co]);
    }
}

// ---------------- per-channel sum/sumsq (training-mode BN stats) ----------------
template <int C, typename T>
__global__ void stats_kernel(const T* __restrict__ in, long long total,
                             float* __restrict__ gsum, float* __restrict__ gsq) {
    __shared__ float s_sum[C];
    __shared__ float s_sq[C];
    int t = threadIdx.x;
    if (t < C) { s_sum[t] = 0.f; s_sq[t] = 0.f; }
    __syncthreads();
    long long stride = (long long)gridDim.x * blockDim.x;  // multiple of C (blockDim=256)
    float ls = 0.f, lq = 0.f;
    for (long long i = (long long)blockIdx.x * blockDim.x + t; i < total; i += stride) {
        float v = ldv(in, i);
        ls += v;
        lq += v * v;
    }
    int c = t & (C - 1);
    atomicAdd(&s_sum[c], ls);
    atomicAdd(&s_sq[c], lq);
    __syncthreads();
    if (t < C) {
        atomicAdd(&gsum[t], s_sum[t]);
        atomicAdd(&gsq[t], s_sq[t]);
    }
}

// ---------------- y = relu((x-m)*rsqrt(v+eps)*g + b), bf16 out ----------------
template <int C, typename T>
__global__ void bn_relu_kernel(const T* __restrict__ in, ushort* __restrict__ out,
                               long long total,
                               const float* __restrict__ gsum, const float* __restrict__ gsq,
                               const float* __restrict__ gamma, const float* __restrict__ beta,
                               float invN) {
    long long stride = (long long)gridDim.x * blockDim.x;
    for (long long i = (long long)blockIdx.x * blockDim.x + threadIdx.x; i < total; i += stride) {
        int c = (int)(i & (C - 1));
        float m = gsum[c] * invN;
        float v = fmaxf(gsq[c] * invN - m * m, 0.f);
        float a = gamma[c] * rsqrtf(v + EPSV);
        float bb = beta[c] - m * a;
        float y = ldv(in, i) * a + bb;
        out[i] = f2bf(fmaxf(y, 0.f));
    }
}

// ---------------- conv1: [N,32] -> [N,64] over 27 offsets, MFMA, bf16 out (pre-BN) -------
__global__ __launch_bounds__(256) void conv1_kernel(const ushort* __restrict__ y1,
                                                    const int* __restrict__ nbr,
                                                    const ushort* __restrict__ w1s,
                                                    ushort* __restrict__ out1) {
    const int lane = threadIdx.x & 63;
    const int wv = threadIdx.x >> 6;
    const int m = lane & 15, g = lane >> 4;
    const int rowbase = blockIdx.x * 64 + wv * 16;
    const int arow = rowbase + m;
    const bool av = arow < NVOX;
    const uint4* __restrict__ yv = (const uint4*)y1;
    const uint4* __restrict__ wvp = (const uint4*)w1s;
    f32x4 acc0 = {0.f, 0.f, 0.f, 0.f}, acc1 = acc0, acc2 = acc0, acc3 = acc0;
#pragma unroll 3
    for (int k = 0; k < KK; k++) {
        int idx = av ? nbr[arow * KK + k] : NVOX;
        idx = (int)min((unsigned)idx, (unsigned)NVOX);  // clamp: OOB-proof gather
        bf16x8 a = as_bf8(yv[idx * 4 + g]);
        acc0 = __builtin_amdgcn_mfma_f32_16x16x32_bf16(a, as_bf8(wvp[(k * 4 + 0) * 64 + lane]), acc0, 0, 0, 0);
        acc1 = __builtin_amdgcn_mfma_f32_16x16x32_bf16(a, as_bf8(wvp[(k * 4 + 1) * 64 + lane]), acc1, 0, 0, 0);
        acc2 = __builtin_amdgcn_mfma_f32_16x16x32_bf16(a, as_bf8(wvp[(k * 4 + 2) * 64 + lane]), acc2, 0, 0, 0);
        acc3 = __builtin_amdgcn_mfma_f32_16x16x32_bf16(a, as_bf8(wvp[(k * 4 + 3) * 64 + lane]), acc3, 0, 0, 0);
    }
    // C/D layout: col = lane&15 (=m), row = g*4 + reg
#pragma unroll
    for (int reg = 0; reg < 4; reg++) {
        int r = rowbase + g * 4 + reg;
        if (r < NVOX) {
            size_t b = (size_t)r * COUT + m;
            out1[b] = f2bf(acc0[reg]);
            out1[b + 16] = f2bf(acc1[reg]);
            out1[b + 32] = f2bf(acc2[reg]);
            out1[b + 48] = f2bf(acc3[reg]);
        }
    }
}

// ---------------- conv2: [N,64] -> [N,64] + fused residual (x@Wres + bres), f32 out -------
__global__ __launch_bounds__(256) void conv2_kernel(const ushort* __restrict__ y2,
                                                    const int* __restrict__ nbr,
                                                    const ushort* __restrict__ w2s,
                                                    const float* __restrict__ x,
                                                    const ushort* __restrict__ wrs,
                                                    const float* __restrict__ bres,
                                                    float* __restrict__ out) {
    const int lane = threadIdx.x & 63;
    const int wv = threadIdx.x >> 6;
    const int m = lane & 15, g = lane >> 4;
    const int rowbase = blockIdx.x * 64 + wv * 16;
    const int arow = rowbase + m;
    const bool av = arow < NVOX;
    const uint4* __restrict__ yv = (const uint4*)y2;
    const uint4* __restrict__ w2v = (const uint4*)w2s;
    const float4* __restrict__ xv = (const float4*)x;
    const uint4* __restrict__ wrv = (const uint4*)wrs;
    f32x4 acc0 = {0.f, 0.f, 0.f, 0.f}, acc1 = acc0, acc2 = acc0, acc3 = acc0;
#pragma unroll 3
    for (int k = 0; k < KK; k++) {
        int idx = av ? nbr[arow * KK + k] : NVOX;
        idx = (int)min((unsigned)idx, (unsigned)NVOX);  // clamp: OOB-proof gather
        bf16x8 a0 = as_bf8(yv[idx * 8 + g]);
        bf16x8 a1 = as_bf8(yv[idx * 8 + 4 + g]);
        acc0 = __builtin_amdgcn_mfma_f32_16x16x32_bf16(a0, as_bf8(w2v[((k * 2 + 0) * 4 + 0) * 64 + lane]), acc0, 0, 0, 0);
        acc0 = __builtin_amdgcn_mfma_f32_16x16x32_bf16(a1, as_bf8(w2v[((k * 2 + 1) * 4 + 0) * 64 + lane]), acc0, 0, 0, 0);
        acc1 = __builtin_amdgcn_mfma_f32_16x16x32_bf16(a0, as_bf8(w2v[((k * 2 + 0) * 4 + 1) * 64 + lane]), acc1, 0, 0, 0);
        acc1 = __builtin_amdgcn_mfma_f32_16x16x32_bf16(a1, as_bf8(w2v[((k * 2 + 1) * 4 + 1) * 64 + lane]), acc1, 0, 0, 0);
        acc2 = __builtin_amdgcn_mfma_f32_16x16x32_bf16(a0, as_bf8(w2v[((k * 2 + 0) * 4 + 2) * 64 + lane]), acc2, 0, 0, 0);
        acc2 = __builtin_amdgcn_mfma_f32_16x16x32_bf16(a1, as_bf8(w2v[((k * 2 + 1) * 4 + 2) * 64 + lane]), acc2, 0, 0, 0);
        acc3 = __builtin_amdgcn_mfma_f32_16x16x32_bf16(a0, as_bf8(w2v[((k * 2 + 0) * 4 + 3) * 64 + lane]), acc3, 0, 0, 0);
        acc3 = __builtin_amdgcn_mfma_f32_16x16x32_bf16(a1, as_bf8(w2v[((k * 2 + 1) * 4 + 3) * 64 + lane]), acc3, 0, 0, 0);
    }
    // residual GEMM: A = x (f32 -> bf16 on the fly, K=32), B = Wres
    bf16x8 ar;
    if (av) {
        float4 f0 = xv[arow * 8 + g * 2];
        float4 f1 = xv[arow * 8 + g * 2 + 1];
        ar = f8_to_bf8(f0, f1);
    } else {
        uint4 zz = {0u, 0u, 0u, 0u};
        ar = as_bf8(zz);
    }
    acc0 = __builtin_amdgcn_mfma_f32_16x16x32_bf16(ar, as_bf8(wrv[0 * 64 + lane]), acc0, 0, 0, 0);
    acc1 = __builtin_amdgcn_mfma_f32_16x16x32_bf16(ar, as_bf8(wrv[1 * 64 + lane]), acc1, 0, 0, 0);
    acc2 = __builtin_amdgcn_mfma_f32_16x16x32_bf16(ar, as_bf8(wrv[2 * 64 + lane]), acc2, 0, 0, 0);
    acc3 = __builtin_amdgcn_mfma_f32_16x16x32_bf16(ar, as_bf8(wrv[3 * 64 + lane]), acc3, 0, 0, 0);

    float br0 = bres[m];
    float br1 = bres[16 + m];
    float br2 = bres[32 + m];
    float br3 = bres[48 + m];
#pragma unroll
    for (int reg = 0; reg < 4; reg++) {
        int r = rowbase + g * 4 + reg;
        if (r < NVOX) {
            size_t b = (size_t)r * COUT + m;
            out[b] = acc0[reg] + br0;
            out[b + 16] = acc1[reg] + br1;
            out[b + 32] = acc2[reg] + br2;
            out[b + 48] = acc3[reg] + br3;
        }
    }
}

extern "C" void kernel_launch(void* const* d_in, const int* in_sizes, int n_in,
                              void* d_out, int out_size, void* d_ws, size_t ws_size,
                              hipStream_t stream) {
    const float* x = (const float*)d_in[0];
    const int* nbr = (const int*)d_in[1];
    const float* W1 = (const float*)d_in[2];
    const float* W2 = (const float*)d_in[3];
    const float* Wres = (const float*)d_in[4];
    const float* bres = (const float*)d_in[5];
    const float* g1 = (const float*)d_in[6];
    const float* b1 = (const float*)d_in[7];
    const float* g2 = (const float*)d_in[8];
    const float* b2 = (const float*)d_in[9];
    float* out = (float*)d_out;

    // Workspace (~97 MB): y1 bf16 32MB, y2 bf16 64MB, weights/stats <0.5MB.
    // conv1's pre-BN bf16 output aliases the first 64MB of d_out (float, 128MB);
    // conv2 rewrites all of d_out afterwards.
    char* ws = (char*)d_ws;
    size_t off = 0;
    auto alloc = [&](size_t bytes) -> void* {
        void* p = ws + off;
        off = (off + bytes + 255) & ~(size_t)255;
        return p;
    };
    ushort* y1 = (ushort*)alloc((size_t)(NVOX + 1) * CIN * 2);    // sentinel row N = zeros
    ushort* y2 = (ushort*)alloc((size_t)(NVOX + 1) * COUT * 2);
    ushort* w1s = (ushort*)alloc(55296 * 2);
    ushort* w2s = (ushort*)alloc(110592 * 2);
    ushort* wrs = (ushort*)alloc(2048 * 2);
    float* stats = (float*)alloc(192 * 4);
    float* sum1 = stats, *sq1 = stats + 32, *sum2 = stats + 64, *sq2 = stats + 128;
    ushort* out1 = (ushort*)d_out;  // bf16 pre-BN conv1 output, first 64MB of d_out

    const float invN = 1.0f / (float)NVOX;
    const int convGrid = (NVOX + 63) / 64;

    hipLaunchKernelGGL(prep_kernel, dim3(658), dim3(256), 0, stream,
                       W1, W2, Wres, w1s, w2s, wrs, stats, y1, y2);
    hipLaunchKernelGGL(HIP_KERNEL_NAME(stats_kernel<32, float>), dim3(1024), dim3(256), 0, stream,
                       x, (long long)NVOX * CIN, sum1, sq1);
    hipLaunchKernelGGL(HIP_KERNEL_NAME(bn_relu_kernel<32, float>), dim3(4096), dim3(256), 0, stream,
                       x, y1, (long long)NVOX * CIN, sum1, sq1, g1, b1, invN);
    hipLaunchKernelGGL(conv1_kernel, dim3(convGrid), dim3(256), 0, stream,
                       y1, nbr, w1s, out1);
    hipLaunchKernelGGL(HIP_KERNEL_NAME(stats_kernel<64, ushort>), dim3(1024), dim3(256), 0, stream,
                       out1, (long long)NVOX * COUT, sum2, sq2);
    hipLaunchKernelGGL(HIP_KERNEL_NAME(bn_relu_kernel<64, ushort>), dim3(4096), dim3(256), 0, stream,
                       out1, y2, (long long)NVOX * COUT, sum2, sq2, g2, b2, invN);
    hipLaunchKernelGGL(conv2_kernel, dim3(convGrid), dim3(256), 0, stream,
                       y2, nbr, w2s, x, wrs, bres, out);
    (void)in_sizes; (void)n_in; (void)out_size; (void)ws_size;
}

// Round 4
// 859.077 us; speedup vs baseline: 1.0810x; 1.0810x over previous
//
#include <hip/hip_runtime.h>

#define NVOX 500000
#define CIN 32
#define COUT 64
#define KK 27
#define EPSV 1e-5f

typedef __bf16 bf16x8 __attribute__((ext_vector_type(8)));
typedef float f32x4 __attribute__((ext_vector_type(4)));

__device__ __forceinline__ float bf2f(ushort u) {
    return __uint_as_float(((unsigned)u) << 16);
}
__device__ __forceinline__ ushort f2bf(float f) {
    unsigned u = __float_as_uint(f);
    unsigned r = (u + 0x7FFFu + ((u >> 16) & 1u)) >> 16;  // RNE
    return (ushort)r;
}
union U4BF { uint4 u; bf16x8 b; ushort s[8]; };
__device__ __forceinline__ bf16x8 as_bf8(uint4 v) { U4BF c; c.u = v; return c.b; }
__device__ __forceinline__ bf16x8 f8_to_bf8(float4 a, float4 b) {
    U4BF c;
    c.s[0] = f2bf(a.x); c.s[1] = f2bf(a.y); c.s[2] = f2bf(a.z); c.s[3] = f2bf(a.w);
    c.s[4] = f2bf(b.x); c.s[5] = f2bf(b.y); c.s[6] = f2bf(b.z); c.s[7] = f2bf(b.w);
    return c.b;
}

__device__ __forceinline__ float4 ldv4(const float4* p, long long i) { return p[i]; }
__device__ __forceinline__ float4 ldv4(const ushort4* p, long long i) {
    ushort4 u = p[i];
    return make_float4(bf2f(u.x), bf2f(u.y), bf2f(u.z), bf2f(u.w));
}

// ---------------- prep: zero stats + sentinel rows, swizzle weights (f32 -> bf16 frags) ----
__global__ void prep_kernel(const float* __restrict__ W1, const float* __restrict__ W2,
                            const float* __restrict__ Wres,
                            ushort* __restrict__ w1s, ushort* __restrict__ w2s,
                            ushort* __restrict__ wrs,
                            float* __restrict__ stats,
                            ushort* __restrict__ y1, ushort* __restrict__ y2) {
    int t = blockIdx.x * 256 + threadIdx.x;
    if (t < 192) { stats[t] = 0.f; return; }
    if (t < 224) { y1[(size_t)NVOX * CIN + (t - 192)] = 0; return; }
    if (t < 288) { y2[(size_t)NVOX * COUT + (t - 224)] = 0; return; }
    int d = t - 288;
    if (d < 27 * 4 * 64 * 8) {  // 55296
        int j = d & 7, lane = (d >> 3) & 63, nt = (d >> 9) & 3, k = d >> 11;
        int ci = ((lane >> 4) << 3) + j, co = (nt << 4) + (lane & 15);
        w1s[d] = f2bf(W1[(k * CIN + ci) * COUT + co]);
        return;
    }
    d -= 27 * 4 * 64 * 8;
    if (d < 27 * 2 * 4 * 64 * 8) {  // 110592
        int j = d & 7, lane = (d >> 3) & 63, nt = (d >> 9) & 3, half = (d >> 11) & 1, k = d >> 12;
        int ci = (half << 5) + ((lane >> 4) << 3) + j, co = (nt << 4) + (lane & 15);
        w2s[d] = f2bf(W2[(k * COUT + ci) * COUT + co]);
        return;
    }
    d -= 27 * 2 * 4 * 64 * 8;
    if (d < 4 * 64 * 8) {  // 2048
        int j = d & 7, lane = (d >> 3) & 63, nt = (d >> 9) & 3;
        int ci = ((lane >> 4) << 3) + j, co = (nt << 4) + (lane & 15);
        wrs[d] = f2bf(Wres[ci * COUT + co]);
    }
}

// ---------------- per-channel sum/sumsq, x4 vectorized ----------------
template <int C, typename T4>
__global__ void stats_kernel(const T4* __restrict__ in, long long total4,
                             float* __restrict__ gsum, float* __restrict__ gsq) {
    __shared__ float s_sum[C];
    __shared__ float s_sq[C];
    int t = threadIdx.x;
    if (t < C) { s_sum[t] = 0.f; s_sq[t] = 0.f; }
    __syncthreads();
    long long i0 = (long long)blockIdx.x * blockDim.x + t;
    long long stride = (long long)gridDim.x * blockDim.x;  // stride*4 multiple of C
    int c0 = (int)((i0 * 4) & (C - 1));
    float ls0 = 0.f, ls1 = 0.f, ls2 = 0.f, ls3 = 0.f;
    float lq0 = 0.f, lq1 = 0.f, lq2 = 0.f, lq3 = 0.f;
    for (long long i = i0; i < total4; i += stride) {
        float4 v = ldv4(in, i);
        ls0 += v.x; lq0 += v.x * v.x;
        ls1 += v.y; lq1 += v.y * v.y;
        ls2 += v.z; lq2 += v.z * v.z;
        ls3 += v.w; lq3 += v.w * v.w;
    }
    atomicAdd(&s_sum[c0 + 0], ls0); atomicAdd(&s_sq[c0 + 0], lq0);
    atomicAdd(&s_sum[c0 + 1], ls1); atomicAdd(&s_sq[c0 + 1], lq1);
    atomicAdd(&s_sum[c0 + 2], ls2); atomicAdd(&s_sq[c0 + 2], lq2);
    atomicAdd(&s_sum[c0 + 3], ls3); atomicAdd(&s_sq[c0 + 3], lq3);
    __syncthreads();
    if (t < C) {
        atomicAdd(&gsum[t], s_sum[t]);
        atomicAdd(&gsq[t], s_sq[t]);
    }
}

// ---------------- y = relu(bn(x)), x4 vectorized, bf16 out ----------------
template <int C, typename T4>
__global__ void bn_relu_kernel(const T4* __restrict__ in, ushort4* __restrict__ out,
                               long long total4,
                               const float* __restrict__ gsum, const float* __restrict__ gsq,
                               const float* __restrict__ gamma, const float* __restrict__ beta,
                               float invN) {
    long long i0 = (long long)blockIdx.x * blockDim.x + threadIdx.x;
    long long stride = (long long)gridDim.x * blockDim.x;
    int c0 = (int)((i0 * 4) & (C - 1));
    float a[4], bb[4];
#pragma unroll
    for (int j = 0; j < 4; j++) {
        int c = c0 + j;
        float m = gsum[c] * invN;
        float v = fmaxf(gsq[c] * invN - m * m, 0.f);
        a[j] = gamma[c] * rsqrtf(v + EPSV);
        bb[j] = beta[c] - m * a[j];
    }
    for (long long i = i0; i < total4; i += stride) {
        float4 v = ldv4(in, i);
        ushort4 o;
        o.x = f2bf(fmaxf(v.x * a[0] + bb[0], 0.f));
        o.y = f2bf(fmaxf(v.y * a[1] + bb[1], 0.f));
        o.z = f2bf(fmaxf(v.z * a[2] + bb[2], 0.f));
        o.w = f2bf(fmaxf(v.w * a[3] + bb[3], 0.f));
        out[i] = o;
    }
}

// ---------------- conv1: [N,32] -> [N,64], pipelined gathers, bf16 out (pre-BN) -------
__global__ __launch_bounds__(256) void conv1_kernel(const ushort* __restrict__ y1,
                                                    const int* __restrict__ nbr,
                                                    const ushort* __restrict__ w1s,
                                                    ushort* __restrict__ out1) {
    const int lane = threadIdx.x & 63;
    const int wv = threadIdx.x >> 6;
    const int m = lane & 15, g = lane >> 4;
    const int rowbase = blockIdx.x * 64 + wv * 16;
    const int arow = rowbase + m;
    const bool av = arow < NVOX;
    const uint4* __restrict__ yv = (const uint4*)y1;
    const uint4* __restrict__ wvp = (const uint4*)w1s;

    // 1) all 27 neighbor indices up front (independent loads, one vmcnt batch)
    int idxs[KK];
#pragma unroll
    for (int k = 0; k < KK; k++) {
        int t = av ? nbr[arow * KK + k] : NVOX;
        idxs[k] = (int)min((unsigned)t, (unsigned)NVOX);
    }
    // 2) pipelined gathers, depth P
    constexpr int P = 8;
    uint4 ga[P];
#pragma unroll
    for (int p = 0; p < P; p++) ga[p] = yv[idxs[p] * 4 + g];

    f32x4 acc0 = {0.f, 0.f, 0.f, 0.f}, acc1 = acc0, acc2 = acc0, acc3 = acc0;
#pragma unroll
    for (int k = 0; k < KK; k++) {
        bf16x8 a = as_bf8(ga[k % P]);
        if (k + P < KK) ga[k % P] = yv[idxs[k + P] * 4 + g];
        acc0 = __builtin_amdgcn_mfma_f32_16x16x32_bf16(a, as_bf8(wvp[(k * 4 + 0) * 64 + lane]), acc0, 0, 0, 0);
        acc1 = __builtin_amdgcn_mfma_f32_16x16x32_bf16(a, as_bf8(wvp[(k * 4 + 1) * 64 + lane]), acc1, 0, 0, 0);
        acc2 = __builtin_amdgcn_mfma_f32_16x16x32_bf16(a, as_bf8(wvp[(k * 4 + 2) * 64 + lane]), acc2, 0, 0, 0);
        acc3 = __builtin_amdgcn_mfma_f32_16x16x32_bf16(a, as_bf8(wvp[(k * 4 + 3) * 64 + lane]), acc3, 0, 0, 0);
    }
    // C/D layout: col = lane&15 (=m), row = g*4 + reg
#pragma unroll
    for (int reg = 0; reg < 4; reg++) {
        int r = rowbase + g * 4 + reg;
        if (r < NVOX) {
            size_t b = (size_t)r * COUT + m;
            out1[b] = f2bf(acc0[reg]);
            out1[b + 16] = f2bf(acc1[reg]);
            out1[b + 32] = f2bf(acc2[reg]);
            out1[b + 48] = f2bf(acc3[reg]);
        }
    }
}

// ---------------- conv2: [N,64] -> [N,64] + fused residual, pipelined gathers, f32 out ----
__global__ __launch_bounds__(256) void conv2_kernel(const ushort* __restrict__ y2,
                                                    const int* __restrict__ nbr,
                                                    const ushort* __restrict__ w2s,
                                                    const float* __restrict__ x,
                                                    const ushort* __restrict__ wrs,
                                                    const float* __restrict__ bres,
                                                    float* __restrict__ out) {
    const int lane = threadIdx.x & 63;
    const int wv = threadIdx.x >> 6;
    const int m = lane & 15, g = lane >> 4;
    const int rowbase = blockIdx.x * 64 + wv * 16;
    const int arow = rowbase + m;
    const bool av = arow < NVOX;
    const uint4* __restrict__ yv = (const uint4*)y2;
    const uint4* __restrict__ w2v = (const uint4*)w2s;
    const float4* __restrict__ xv = (const float4*)x;
    const uint4* __restrict__ wrv = (const uint4*)wrs;

    int idxs[KK];
#pragma unroll
    for (int k = 0; k < KK; k++) {
        int t = av ? nbr[arow * KK + k] : NVOX;
        idxs[k] = (int)min((unsigned)t, (unsigned)NVOX);
    }
    constexpr int P = 6;
    uint4 ga0[P], ga1[P];
#pragma unroll
    for (int p = 0; p < P; p++) {
        ga0[p] = yv[idxs[p] * 8 + g];
        ga1[p] = yv[idxs[p] * 8 + 4 + g];
    }

    f32x4 acc0 = {0.f, 0.f, 0.f, 0.f}, acc1 = acc0, acc2 = acc0, acc3 = acc0;
#pragma unroll
    for (int k = 0; k < KK; k++) {
        bf16x8 a0 = as_bf8(ga0[k % P]);
        bf16x8 a1 = as_bf8(ga1[k % P]);
        if (k + P < KK) {
            ga0[k % P] = yv[idxs[k + P] * 8 + g];
            ga1[k % P] = yv[idxs[k + P] * 8 + 4 + g];
        }
        acc0 = __builtin_amdgcn_mfma_f32_16x16x32_bf16(a0, as_bf8(w2v[((k * 2 + 0) * 4 + 0) * 64 + lane]), acc0, 0, 0, 0);
        acc0 = __builtin_amdgcn_mfma_f32_16x16x32_bf16(a1, as_bf8(w2v[((k * 2 + 1) * 4 + 0) * 64 + lane]), acc0, 0, 0, 0);
        acc1 = __builtin_amdgcn_mfma_f32_16x16x32_bf16(a0, as_bf8(w2v[((k * 2 + 0) * 4 + 1) * 64 + lane]), acc1, 0, 0, 0);
        acc1 = __builtin_amdgcn_mfma_f32_16x16x32_bf16(a1, as_bf8(w2v[((k * 2 + 1) * 4 + 1) * 64 + lane]), acc1, 0, 0, 0);
        acc2 = __builtin_amdgcn_mfma_f32_16x16x32_bf16(a0, as_bf8(w2v[((k * 2 + 0) * 4 + 2) * 64 + lane]), acc2, 0, 0, 0);
        acc2 = __builtin_amdgcn_mfma_f32_16x16x32_bf16(a1, as_bf8(w2v[((k * 2 + 1) * 4 + 2) * 64 + lane]), acc2, 0, 0, 0);
        acc3 = __builtin_amdgcn_mfma_f32_16x16x32_bf16(a0, as_bf8(w2v[((k * 2 + 0) * 4 + 3) * 64 + lane]), acc3, 0, 0, 0);
        acc3 = __builtin_amdgcn_mfma_f32_16x16x32_bf16(a1, as_bf8(w2v[((k * 2 + 1) * 4 + 3) * 64 + lane]), acc3, 0, 0, 0);
    }
    // residual GEMM: A = x (f32 -> bf16 on the fly, K=32), B = Wres
    bf16x8 ar;
    if (av) {
        float4 f0 = xv[arow * 8 + g * 2];
        float4 f1 = xv[arow * 8 + g * 2 + 1];
        ar = f8_to_bf8(f0, f1);
    } else {
        uint4 zz = {0u, 0u, 0u, 0u};
        ar = as_bf8(zz);
    }
    acc0 = __builtin_amdgcn_mfma_f32_16x16x32_bf16(ar, as_bf8(wrv[0 * 64 + lane]), acc0, 0, 0, 0);
    acc1 = __builtin_amdgcn_mfma_f32_16x16x32_bf16(ar, as_bf8(wrv[1 * 64 + lane]), acc1, 0, 0, 0);
    acc2 = __builtin_amdgcn_mfma_f32_16x16x32_bf16(ar, as_bf8(wrv[2 * 64 + lane]), acc2, 0, 0, 0);
    acc3 = __builtin_amdgcn_mfma_f32_16x16x32_bf16(ar, as_bf8(wrv[3 * 64 + lane]), acc3, 0, 0, 0);

    float br0 = bres[m];
    float br1 = bres[16 + m];
    float br2 = bres[32 + m];
    float br3 = bres[48 + m];
#pragma unroll
    for (int reg = 0; reg < 4; reg++) {
        int r = rowbase + g * 4 + reg;
        if (r < NVOX) {
            size_t b = (size_t)r * COUT + m;
            out[b] = acc0[reg] + br0;
            out[b + 16] = acc1[reg] + br1;
            out[b + 32] = acc2[reg] + br2;
            out[b + 48] = acc3[reg] + br3;
        }
    }
}

extern "C" void kernel_launch(void* const* d_in, const int* in_sizes, int n_in,
                              void* d_out, int out_size, void* d_ws, size_t ws_size,
                              hipStream_t stream) {
    const float* x = (const float*)d_in[0];
    const int* nbr = (const int*)d_in[1];
    const float* W1 = (const float*)d_in[2];
    const float* W2 = (const float*)d_in[3];
    const float* Wres = (const float*)d_in[4];
    const float* bres = (const float*)d_in[5];
    const float* g1 = (const float*)d_in[6];
    const float* b1 = (const float*)d_in[7];
    const float* g2 = (const float*)d_in[8];
    const float* b2 = (const float*)d_in[9];
    float* out = (float*)d_out;

    // Workspace (~97 MB): y1 bf16 32MB, y2 bf16 64MB, weights/stats <0.5MB.
    // conv1's pre-BN bf16 output aliases the first 64MB of d_out (float, 128MB);
    // conv2 rewrites all of d_out afterwards.
    char* ws = (char*)d_ws;
    size_t off = 0;
    auto alloc = [&](size_t bytes) -> void* {
        void* p = ws + off;
        off = (off + bytes + 255) & ~(size_t)255;
        return p;
    };
    ushort* y1 = (ushort*)alloc((size_t)(NVOX + 1) * CIN * 2);    // sentinel row N = zeros
    ushort* y2 = (ushort*)alloc((size_t)(NVOX + 1) * COUT * 2);
    ushort* w1s = (ushort*)alloc(55296 * 2);
    ushort* w2s = (ushort*)alloc(110592 * 2);
    ushort* wrs = (ushort*)alloc(2048 * 2);
    float* stats = (float*)alloc(192 * 4);
    float* sum1 = stats, *sq1 = stats + 32, *sum2 = stats + 64, *sq2 = stats + 128;
    ushort* out1 = (ushort*)d_out;  // bf16 pre-BN conv1 output, first 64MB of d_out

    const float invN = 1.0f / (float)NVOX;
    const int convGrid = (NVOX + 63) / 64;
    const long long tot1 = (long long)NVOX * CIN / 4;   // float4/ushort4 groups
    const long long tot2 = (long long)NVOX * COUT / 4;

    hipLaunchKernelGGL(prep_kernel, dim3(658), dim3(256), 0, stream,
                       W1, W2, Wres, w1s, w2s, wrs, stats, y1, y2);
    hipLaunchKernelGGL(HIP_KERNEL_NAME(stats_kernel<32, float4>), dim3(1024), dim3(256), 0, stream,
                       (const float4*)x, tot1, sum1, sq1);
    hipLaunchKernelGGL(HIP_KERNEL_NAME(bn_relu_kernel<32, float4>), dim3(2048), dim3(256), 0, stream,
                       (const float4*)x, (ushort4*)y1, tot1, sum1, sq1, g1, b1, invN);
    hipLaunchKernelGGL(conv1_kernel, dim3(convGrid), dim3(256), 0, stream,
                       y1, nbr, w1s, out1);
    hipLaunchKernelGGL(HIP_KERNEL_NAME(stats_kernel<64, ushort4>), dim3(1024), dim3(256), 0, stream,
                       (const ushort4*)out1, tot2, sum2, sq2);
    hipLaunchKernelGGL(HIP_KERNEL_NAME(bn_relu_kernel<64, ushort4>), dim3(2048), dim3(256), 0, stream,
                       (const ushort4*)out1, (ushort4*)y2, tot2, sum2, sq2, g2, b2, invN);
    hipLaunchKernelGGL(conv2_kernel, dim3(convGrid), dim3(256), 0, stream,
                       y2, nbr, w2s, x, wrs, bres, out);
    (void)in_sizes; (void)n_in; (void)out_size; (void)ws_size;
}